// Round 4
// baseline (159.931 us; speedup 1.0000x reference)
//
#include <hip/hip_runtime.h>

// LowRankSig_HigherOrder: B=32, T=2048, F=64 (time + 63), K=10 tensors, U=64 units.
// Affine-scan decomposition (validated exact rounds 1-3). Each wave (64 lanes =
// 64 units) handles a 16-row sub-chunk: computes the M-DIFF tile on the fly
// (fp32 dot products of dXa rows staged in LDS with kernel columns streamed
// from L2), scans with zero init state, and writes a 17-parameter affine map
// of the carried state (c1,c3,cA,c6,cP,cQ). A tiny second kernel folds the
// 128 maps sequentially per (b,u).
//
// Round-4 changes vs round 3 (148 us, spill-bound):
//  - NO __launch_bounds__ occupancy arg (r2/r3 showed it makes the allocator
//    target 2x the waves and spill: VGPR capped 48/64, WRITE_SIZE 235 MB).
//    Instead amdgpu_waves_per_eu(4,4) pins the budget at exactly 128 VGPRs.
//  - Phase C split into two 8-row passes (acc 16x4 -> 8x4, peak live ~-32
//    regs), scan state carried between passes. Fits 128 without spill.

#define TT 2048
#define NFX 63
#define KT 10
#define NU 64
#define NQ 17
#define NCC 128      // 16-row sub-chunks per batch (ws layout)
#define TSTRIDE 68   // padded row stride (floats) for dXa [f][row], 64 rows

template<int KP, int NR>
__device__ __forceinline__ void compute_md(
    const float* __restrict__ Kw, const float* __restrict__ dXa,
    int rowbase, int u, int kbase, float (&acc)[NR][KP])
{
#pragma unroll
  for (int r = 0; r < NR; ++r)
#pragma unroll
    for (int k = 0; k < KP; ++k) acc[r][k] = 0.f;

  const float* kp = &Kw[kbase * NU + u];
  float kvn[KP];
#pragma unroll
  for (int k = 0; k < KP; ++k) kvn[k] = kp[k * NU];

  for (int f = 0; f < 64; ++f) {
    float kv[KP];
#pragma unroll
    for (int k = 0; k < KP; ++k) kv[k] = kvn[k];
    kp += KT * NU;
    if (f < 63) {
#pragma unroll
      for (int k = 0; k < KP; ++k) kvn[k] = kp[k * NU];
    }
    const float* xb = &dXa[f * TSTRIDE + rowbase];
#pragma unroll
    for (int r4 = 0; r4 < NR / 4; ++r4) {
      float4 v = *reinterpret_cast<const float4*>(xb + 4 * r4);
#pragma unroll
      for (int k = 0; k < KP; ++k) {
        acc[4*r4+0][k] = fmaf(v.x, kv[k], acc[4*r4+0][k]);
        acc[4*r4+1][k] = fmaf(v.y, kv[k], acc[4*r4+1][k]);
        acc[4*r4+2][k] = fmaf(v.z, kv[k], acc[4*r4+2][k]);
        acc[4*r4+3][k] = fmaf(v.w, kv[k], acc[4*r4+3][k]);
      }
    }
  }
}

__global__ __attribute__((amdgpu_flat_work_group_size(256, 256)))
__attribute__((amdgpu_waves_per_eu(4, 4)))
void lrsig_chunk_kernel(const float* __restrict__ X,
                        const float* __restrict__ Kw,
                        float* __restrict__ ws)
{
  __shared__ float dXa[64 * TSTRIDE];   // diff tile, transposed [f][row]

  const int b = blockIdx.y;
  const int c = blockIdx.x;          // 0..31, 64 rows per WG
  const int tid = threadIdx.x;
  const int u = tid & 63;
  const int w = tid >> 6;            // wave 0..3, rows [16w, 16w+16)
  const int t0 = c * 64;

  // ---- stage diff tile: dXa[f][r] = Xa[b,t0+r,f] - Xa[b,t0+r-1,f] (0 at t=0)
  for (int idx = tid; idx < 64 * NFX; idx += 256) {
    int row = idx / NFX;
    int col = idx - row * NFX;
    int gt = t0 + row;
    float d;
    if (gt == 0) d = 0.f;
    else {
      const float* px = &X[((size_t)b * TT + gt) * NFX + col];
      d = px[0] - px[-NFX];
    }
    dXa[(col + 1) * TSTRIDE + row] = d;
  }
  if (tid < 64) {
    dXa[tid] = (t0 + tid == 0) ? 0.f : (2.0f / 2047.0f);   // time feature f=0
  }
  __syncthreads();

  const int rowbase = 16 * w;
  float outq[NQ];

  // ---------- phase A: k = 0,1,2  (level-0 + m=1 chain) ----------
  {
    float acc[16][3];
    compute_md<3, 16>(Kw, dXa, rowbase, u, 0, acc);
    float oA = 0.f, a1 = 0.f, lc1 = 0.f;
#pragma unroll
    for (int t = 0; t < 16; ++t) {
      float m0 = acc[t][0], m1 = acc[t][1], m2 = acc[t][2];
      oA += m0 + m2 * (lc1 + 0.5f * m1);
      a1 += m2;
      lc1 += m1;
    }
    outq[0] = oA; outq[1] = a1; outq[7] = lc1;
  }

  // ---------- phase B: k = 3,4,5  (m=2 chain) ----------
  {
    float acc[16][3];
    compute_md<3, 16>(Kw, dXa, rowbase, u, 3, acc);
    float oB = 0.f, a3 = 0.f, aA = 0.f;
    float lc3 = 0.f, lcA = 0.f, g4 = 0.f;
#pragma unroll
    for (int t = 0; t < 16; ++t) {
      float m3 = acc[t][0], m4 = acc[t][1], m5 = acc[t][2];
      float s0 = m4 * lc3;
      float s1 = 0.5f * m4 * m3;
      oB += m5 * (lcA + 0.5f * s0 + (1.f/3.f) * s1);
      a3 += m5 * (g4 + 0.5f * m4);
      aA += m5;
      lcA += s0 + s1;
      g4  += m4;
      lc3 += m3;
    }
    outq[0] += oB;
    outq[2] = a3; outq[3] = aA; outq[8] = lc3; outq[9] = lcA; outq[13] = g4;
  }

  // ---------- phase C: k = 6,7,8,9  (m=3 chain), two 8-row passes ----------
  {
    float oC = 0.f, a6 = 0.f, aP = 0.f, aQ = 0.f;
    float lc6 = 0.f, lcP = 0.f, lcQ = 0.f, g7 = 0.f, g8 = 0.f, h = 0.f;
#pragma unroll
    for (int half = 0; half < 2; ++half) {
      float acc[8][4];
      compute_md<4, 8>(Kw, dXa, rowbase + 8 * half, u, 6, acc);
#pragma unroll
      for (int t = 0; t < 8; ++t) {
        float m6 = acc[t][0], m7 = acc[t][1], m8 = acc[t][2], m9 = acc[t][3];
        float p0 = m7 * lc6;
        float p1 = 0.5f * m7 * m6;
        float q0 = m8 * lcP;
        float q1 = 0.5f * m8 * p0;
        float q2 = (1.f/3.f) * m8 * p1;
        oC += m9 * (lcQ + 0.5f * q0 + (1.f/3.f) * q1 + 0.25f * q2);
        a6 += m9 * (h + m8 * (0.5f * g7 + (1.f/6.f) * m7));
        aP += m9 * (g8 + 0.5f * m8);
        aQ += m9;
        h  += m8 * (g7 + 0.5f * m7);   // exclusive g7, before update
        lcP += p0 + p1;
        lcQ += q0 + q1 + q2;
        g7 += m7; g8 += m8; lc6 += m6;
      }
    }
    outq[0] += oC;
    outq[4] = a6; outq[5] = aP; outq[6] = aQ;
    outq[10] = lc6; outq[11] = lcP; outq[12] = lcQ;
    outq[14] = g7; outq[15] = g8; outq[16] = h;
  }

  // ---- write 17 scalars, coalesced over u ----
  const int cc = c * 4 + w;          // global sub-chunk index, time-ordered
  float* p = &ws[(((size_t)b * NCC + cc) * NQ) * NU + u];
#pragma unroll
  for (int q = 0; q < NQ; ++q) p[q * NU] = outq[q];
}

__global__ __launch_bounds__(256)
void lrsig_combine_kernel(const float* __restrict__ ws, float* __restrict__ out)
{
  const int gid = blockIdx.x * blockDim.x + threadIdx.x;   // 0..2047
  const int u = gid & 63;
  const int b = gid >> 6;
  float c1 = 0.f, c3 = 0.f, cA = 0.f, c6 = 0.f, cP = 0.f, cQ = 0.f, o = 0.f;
  for (int cc = 0; cc < NCC; ++cc) {
    const float* p = &ws[(((size_t)b * NCC + cc) * NQ) * NU + u];
    float q[NQ];
#pragma unroll
    for (int i = 0; i < NQ; ++i) q[i] = p[i * NU];
    o  += q[0] + q[1]*c1 + q[2]*c3 + q[3]*cA + q[4]*c6 + q[5]*cP + q[6]*cQ;
    cA += q[13]*c3 + q[9];             // uses c3_in
    cQ += q[15]*cP + q[16]*c6 + q[12]; // uses cP_in, c6_in
    cP += q[14]*c6 + q[11];            // uses c6_in
    c1 += q[7]; c3 += q[8]; c6 += q[10];
  }
  out[gid] = o;
}

extern "C" void kernel_launch(void* const* d_in, const int* in_sizes, int n_in,
                              void* d_out, int out_size, void* d_ws, size_t ws_size,
                              hipStream_t stream) {
  const float* X  = (const float*)d_in[0];   // (32, 2048, 63) fp32
  const float* Kw = (const float*)d_in[1];   // (64, 10, 64)   fp32
  float* out = (float*)d_out;                // (32, 64)       fp32
  float* ws  = (float*)d_ws;                 // 32*128*17*64*4 = 17.8 MB

  hipLaunchKernelGGL(lrsig_chunk_kernel, dim3(32, 32), dim3(256), 0, stream,
                     X, Kw, ws);
  hipLaunchKernelGGL(lrsig_combine_kernel, dim3(8), dim3(256), 0, stream,
                     ws, out);
}

// Round 5
// 144.744 us; speedup vs baseline: 1.1049x; 1.1049x over previous
//
#include <hip/hip_runtime.h>

// LowRankSig_HigherOrder: B=32, T=2048, F=64 (time + 63), K=10 tensors, U=64 units.
// Affine-scan decomposition (validated exact rounds 1-4). Each wave (64 lanes =
// 64 units) handles a 16-row sub-chunk: computes the M-DIFF tile on the fly
// (fp32 dot products of dXa rows staged in LDS with kernel columns streamed
// from L2), scans with zero init state, and writes a 17-parameter affine map
// of the carried state (c1,c3,cA,c6,cP,cQ). A tiny second kernel folds the
// 128 maps sequentially per (b,u).
//
// Round-5 changes vs round 4 (160 us, still spill-bound):
//  - NO occupancy attribute AT ALL. Evidence r2/r3/r4: any occupancy hint
//    (__launch_bounds__ 2nd arg OR amdgpu_waves_per_eu) makes the allocator
//    pick a half-size file (48/64 VGPR) and spill ~350 MB to scratch.
//    Round 1's bare __launch_bounds__(256) allocated honestly (132, 0 spill).
//  - Instead, peak pressure is reduced STRUCTURALLY: every phase now runs as
//    two 8-row passes (acc tile <= 8x4 = 32 regs), with the 19 scan scalars
//    carried across the halves. Natural allocation should land ~90-120,
//    under the 128-VGPR / 4-waves-per-SIMD cliff -> whole 1024-WG grid
//    resident, no spill.

#define TT 2048
#define NFX 63
#define KT 10
#define NU 64
#define NQ 17
#define NCC 128      // 16-row sub-chunks per batch (ws layout)
#define TSTRIDE 68   // padded row stride (floats) for dXa [f][row], 64 rows

template<int KP>
__device__ __forceinline__ void compute_md8(
    const float* __restrict__ Kw, const float* __restrict__ dXa,
    int rowbase, int u, int kbase, float (&acc)[8][KP])
{
#pragma unroll
  for (int r = 0; r < 8; ++r)
#pragma unroll
    for (int k = 0; k < KP; ++k) acc[r][k] = 0.f;

  const float* kp = &Kw[kbase * NU + u];
  float kvn[KP];
#pragma unroll
  for (int k = 0; k < KP; ++k) kvn[k] = kp[k * NU];

  for (int f = 0; f < 64; ++f) {
    float kv[KP];
#pragma unroll
    for (int k = 0; k < KP; ++k) kv[k] = kvn[k];
    kp += KT * NU;
    if (f < 63) {
#pragma unroll
      for (int k = 0; k < KP; ++k) kvn[k] = kp[k * NU];
    }
    const float* xb = &dXa[f * TSTRIDE + rowbase];
#pragma unroll
    for (int r4 = 0; r4 < 2; ++r4) {
      float4 v = *reinterpret_cast<const float4*>(xb + 4 * r4);
#pragma unroll
      for (int k = 0; k < KP; ++k) {
        acc[4*r4+0][k] = fmaf(v.x, kv[k], acc[4*r4+0][k]);
        acc[4*r4+1][k] = fmaf(v.y, kv[k], acc[4*r4+1][k]);
        acc[4*r4+2][k] = fmaf(v.z, kv[k], acc[4*r4+2][k]);
        acc[4*r4+3][k] = fmaf(v.w, kv[k], acc[4*r4+3][k]);
      }
    }
  }
}

__global__ __launch_bounds__(256)
void lrsig_chunk_kernel(const float* __restrict__ X,
                        const float* __restrict__ Kw,
                        float* __restrict__ ws)
{
  __shared__ float dXa[64 * TSTRIDE];   // diff tile, transposed [f][row]

  const int b = blockIdx.y;
  const int c = blockIdx.x;          // 0..31, 64 rows per WG
  const int tid = threadIdx.x;
  const int u = tid & 63;
  const int w = tid >> 6;            // wave 0..3, rows [16w, 16w+16)
  const int t0 = c * 64;

  // ---- stage diff tile: dXa[f][r] = Xa[b,t0+r,f] - Xa[b,t0+r-1,f] (0 at t=0)
  for (int idx = tid; idx < 64 * NFX; idx += 256) {
    int row = idx / NFX;
    int col = idx - row * NFX;
    int gt = t0 + row;
    float d;
    if (gt == 0) d = 0.f;
    else {
      const float* px = &X[((size_t)b * TT + gt) * NFX + col];
      d = px[0] - px[-NFX];
    }
    dXa[(col + 1) * TSTRIDE + row] = d;
  }
  if (tid < 64) {
    dXa[tid] = (t0 + tid == 0) ? 0.f : (2.0f / 2047.0f);   // time feature f=0
  }
  __syncthreads();

  const int rowbase = 16 * w;

  // persistent scan state (19 scalars), zero-init; updated across 2 halves
  float oA = 0.f, a1 = 0.f, lc1 = 0.f;
  float oB = 0.f, a3 = 0.f, aA = 0.f, lc3 = 0.f, lcA = 0.f, g4 = 0.f;
  float oC = 0.f, a6 = 0.f, aP = 0.f, aQ = 0.f;
  float lc6 = 0.f, lcP = 0.f, lcQ = 0.f, g7 = 0.f, g8 = 0.f, h = 0.f;

#pragma unroll
  for (int half = 0; half < 2; ++half) {
    const int rb = rowbase + 8 * half;

    // ---------- phase A: k = 0,1,2 ----------
    {
      float acc[8][3];
      compute_md8<3>(Kw, dXa, rb, u, 0, acc);
#pragma unroll
      for (int t = 0; t < 8; ++t) {
        float m0 = acc[t][0], m1 = acc[t][1], m2 = acc[t][2];
        oA += m0 + m2 * (lc1 + 0.5f * m1);
        a1 += m2;
        lc1 += m1;
      }
    }

    // ---------- phase B: k = 3,4,5 ----------
    {
      float acc[8][3];
      compute_md8<3>(Kw, dXa, rb, u, 3, acc);
#pragma unroll
      for (int t = 0; t < 8; ++t) {
        float m3 = acc[t][0], m4 = acc[t][1], m5 = acc[t][2];
        float s0 = m4 * lc3;
        float s1 = 0.5f * m4 * m3;
        oB += m5 * (lcA + 0.5f * s0 + (1.f/3.f) * s1);
        a3 += m5 * (g4 + 0.5f * m4);
        aA += m5;
        lcA += s0 + s1;
        g4  += m4;
        lc3 += m3;
      }
    }

    // ---------- phase C: k = 6,7,8,9 ----------
    {
      float acc[8][4];
      compute_md8<4>(Kw, dXa, rb, u, 6, acc);
#pragma unroll
      for (int t = 0; t < 8; ++t) {
        float m6 = acc[t][0], m7 = acc[t][1], m8 = acc[t][2], m9 = acc[t][3];
        float p0 = m7 * lc6;
        float p1 = 0.5f * m7 * m6;
        float q0 = m8 * lcP;
        float q1 = 0.5f * m8 * p0;
        float q2 = (1.f/3.f) * m8 * p1;
        oC += m9 * (lcQ + 0.5f * q0 + (1.f/3.f) * q1 + 0.25f * q2);
        a6 += m9 * (h + m8 * (0.5f * g7 + (1.f/6.f) * m7));
        aP += m9 * (g8 + 0.5f * m8);
        aQ += m9;
        h  += m8 * (g7 + 0.5f * m7);   // exclusive g7, before update
        lcP += p0 + p1;
        lcQ += q0 + q1 + q2;
        g7 += m7; g8 += m8; lc6 += m6;
      }
    }
  }

  // ---- write 17 scalars, coalesced over u ----
  float outq[NQ];
  outq[0] = oA + oB + oC;
  outq[1] = a1;  outq[2] = a3;  outq[3] = aA;
  outq[4] = a6;  outq[5] = aP;  outq[6] = aQ;
  outq[7] = lc1; outq[8] = lc3; outq[9] = lcA;
  outq[10] = lc6; outq[11] = lcP; outq[12] = lcQ;
  outq[13] = g4; outq[14] = g7; outq[15] = g8; outq[16] = h;

  const int cc = c * 4 + w;          // global sub-chunk index, time-ordered
  float* p = &ws[(((size_t)b * NCC + cc) * NQ) * NU + u];
#pragma unroll
  for (int q = 0; q < NQ; ++q) p[q * NU] = outq[q];
}

__global__ __launch_bounds__(256)
void lrsig_combine_kernel(const float* __restrict__ ws, float* __restrict__ out)
{
  const int gid = blockIdx.x * blockDim.x + threadIdx.x;   // 0..2047
  const int u = gid & 63;
  const int b = gid >> 6;
  float c1 = 0.f, c3 = 0.f, cA = 0.f, c6 = 0.f, cP = 0.f, cQ = 0.f, o = 0.f;
  for (int cc = 0; cc < NCC; ++cc) {
    const float* p = &ws[(((size_t)b * NCC + cc) * NQ) * NU + u];
    float q[NQ];
#pragma unroll
    for (int i = 0; i < NQ; ++i) q[i] = p[i * NU];
    o  += q[0] + q[1]*c1 + q[2]*c3 + q[3]*cA + q[4]*c6 + q[5]*cP + q[6]*cQ;
    cA += q[13]*c3 + q[9];             // uses c3_in
    cQ += q[15]*cP + q[16]*c6 + q[12]; // uses cP_in, c6_in
    cP += q[14]*c6 + q[11];            // uses c6_in
    c1 += q[7]; c3 += q[8]; c6 += q[10];
  }
  out[gid] = o;
}

extern "C" void kernel_launch(void* const* d_in, const int* in_sizes, int n_in,
                              void* d_out, int out_size, void* d_ws, size_t ws_size,
                              hipStream_t stream) {
  const float* X  = (const float*)d_in[0];   // (32, 2048, 63) fp32
  const float* Kw = (const float*)d_in[1];   // (64, 10, 64)   fp32
  float* out = (float*)d_out;                // (32, 64)       fp32
  float* ws  = (float*)d_ws;                 // 32*128*17*64*4 = 17.8 MB

  hipLaunchKernelGGL(lrsig_chunk_kernel, dim3(32, 32), dim3(256), 0, stream,
                     X, Kw, ws);
  hipLaunchKernelGGL(lrsig_combine_kernel, dim3(8), dim3(256), 0, stream,
                     ws, out);
}

// Round 6
// 116.389 us; speedup vs baseline: 1.3741x; 1.2436x over previous
//
#include <hip/hip_runtime.h>

// LowRankSig_HigherOrder: B=32, T=2048, F=64 (time + 63), K=10 tensors, U=64 units.
// Affine-scan decomposition (validated exact rounds 1-5). Each wave (64 lanes =
// 64 units) handles a 16-row sub-chunk: computes the M-DIFF tile on the fly
// (fp32 dot products of dXa rows staged in LDS with kernel columns streamed
// from L2), scans with zero init state, writes a 17-parameter affine map.
// A tiny second kernel folds the 128 maps sequentially per (b,u).
//
// Round-6 changes vs round 5 (128 us kernel, VALUBusy 57%):
//  - ONE fused f-pass with acc[16][10] (160 VGPRs) instead of 6 passes
//    (3 phases x 2 halves). Halves Kw L2 traffic (10 loads/f vs 20),
//    removes 5x of loop/prefetch/address overhead, and gives each f-step
//    ~380 cyc of FMA work so the one-f-ahead kv prefetch fully hides L2
//    latency even at 2 waves/SIMD.
//  - NO occupancy attribute (r2/r3/r4: any hint => allocator picks a
//    half-size file and spills ~350 MB; bare __launch_bounds__(256) is
//    honest). Natural demand ~210 regs -> 2 waves/SIMD, no spill.
//  - Scan chains A/B/C are independent -> fused into one t-loop.

#define TT 2048
#define NFX 63
#define KT 10
#define NU 64
#define NQ 17
#define NCC 128      // 16-row sub-chunks per batch (ws layout)
#define TSTRIDE 68   // padded row stride (floats) for dXa [f][row], 64 rows

__global__ __launch_bounds__(256)
void lrsig_chunk_kernel(const float* __restrict__ X,
                        const float* __restrict__ Kw,
                        float* __restrict__ ws)
{
  __shared__ float dXa[64 * TSTRIDE];   // diff tile, transposed [f][row]

  const int b = blockIdx.y;
  const int c = blockIdx.x;          // 0..31, 64 rows per WG
  const int tid = threadIdx.x;
  const int u = tid & 63;
  const int w = tid >> 6;            // wave 0..3, rows [16w, 16w+16)
  const int t0 = c * 64;

  // ---- stage diff tile: dXa[f][r] = Xa[b,t0+r,f] - Xa[b,t0+r-1,f] (0 at t=0)
  for (int idx = tid; idx < 64 * NFX; idx += 256) {
    int row = idx / NFX;
    int col = idx - row * NFX;
    int gt = t0 + row;
    float d;
    if (gt == 0) d = 0.f;
    else {
      const float* px = &X[((size_t)b * TT + gt) * NFX + col];
      d = px[0] - px[-NFX];
    }
    dXa[(col + 1) * TSTRIDE + row] = d;
  }
  if (tid < 64) {
    dXa[tid] = (t0 + tid == 0) ? 0.f : (2.0f / 2047.0f);   // time feature f=0
  }
  __syncthreads();

  const int rowbase = 16 * w;

  // ---- single fused M-diff pass: acc[t][k] for 16 rows x 10 tensors ----
  float acc[16][10];
#pragma unroll
  for (int t = 0; t < 16; ++t)
#pragma unroll
    for (int k = 0; k < 10; ++k) acc[t][k] = 0.f;

  {
    const float* kp = &Kw[u];          // [f][k][u]: k stride NU, f stride KT*NU
    float kvn[10];
#pragma unroll
    for (int k = 0; k < 10; ++k) kvn[k] = kp[k * NU];

    for (int f = 0; f < 64; ++f) {
      float kv[10];
#pragma unroll
      for (int k = 0; k < 10; ++k) kv[k] = kvn[k];
      kp += KT * NU;
      if (f < 63) {
#pragma unroll
        for (int k = 0; k < 10; ++k) kvn[k] = kp[k * NU];
      }
      const float* xb = &dXa[f * TSTRIDE + rowbase];
#pragma unroll
      for (int r4 = 0; r4 < 4; ++r4) {
        float4 v = *reinterpret_cast<const float4*>(xb + 4 * r4);
#pragma unroll
        for (int k = 0; k < 10; ++k) {
          acc[4*r4+0][k] = fmaf(v.x, kv[k], acc[4*r4+0][k]);
          acc[4*r4+1][k] = fmaf(v.y, kv[k], acc[4*r4+1][k]);
          acc[4*r4+2][k] = fmaf(v.z, kv[k], acc[4*r4+2][k]);
          acc[4*r4+3][k] = fmaf(v.w, kv[k], acc[4*r4+3][k]);
        }
      }
    }
  }

  // ---- fused scan over the 16 rows (chains A/B/C are independent) ----
  float o = 0.f, a1 = 0.f, lc1 = 0.f;
  float a3 = 0.f, aA = 0.f, lc3 = 0.f, lcA = 0.f, g4 = 0.f;
  float a6 = 0.f, aP = 0.f, aQ = 0.f;
  float lc6 = 0.f, lcP = 0.f, lcQ = 0.f, g7 = 0.f, g8 = 0.f, h = 0.f;

#pragma unroll
  for (int t = 0; t < 16; ++t) {
    float m0 = acc[t][0], m1 = acc[t][1], m2 = acc[t][2];
    float m3 = acc[t][3], m4 = acc[t][4], m5 = acc[t][5];
    float m6 = acc[t][6], m7 = acc[t][7], m8 = acc[t][8], m9 = acc[t][9];

    // chain A (level 0 + m=1)
    o   += m0 + m2 * (lc1 + 0.5f * m1);
    a1  += m2;
    lc1 += m1;

    // chain B (m=2)
    {
      float s0 = m4 * lc3;
      float s1 = 0.5f * m4 * m3;
      o   += m5 * (lcA + 0.5f * s0 + (1.f/3.f) * s1);
      a3  += m5 * (g4 + 0.5f * m4);
      aA  += m5;
      lcA += s0 + s1;
      g4  += m4;
      lc3 += m3;
    }

    // chain C (m=3)
    {
      float p0 = m7 * lc6;
      float p1 = 0.5f * m7 * m6;
      float q0 = m8 * lcP;
      float q1 = 0.5f * m8 * p0;
      float q2 = (1.f/3.f) * m8 * p1;
      o   += m9 * (lcQ + 0.5f * q0 + (1.f/3.f) * q1 + 0.25f * q2);
      a6  += m9 * (h + m8 * (0.5f * g7 + (1.f/6.f) * m7));
      aP  += m9 * (g8 + 0.5f * m8);
      aQ  += m9;
      h   += m8 * (g7 + 0.5f * m7);   // exclusive g7, before update
      lcP += p0 + p1;
      lcQ += q0 + q1 + q2;
      g7 += m7; g8 += m8; lc6 += m6;
    }
  }

  // ---- write 17 scalars, coalesced over u ----
  float outq[NQ];
  outq[0] = o;
  outq[1] = a1;  outq[2] = a3;  outq[3] = aA;
  outq[4] = a6;  outq[5] = aP;  outq[6] = aQ;
  outq[7] = lc1; outq[8] = lc3; outq[9] = lcA;
  outq[10] = lc6; outq[11] = lcP; outq[12] = lcQ;
  outq[13] = g4; outq[14] = g7; outq[15] = g8; outq[16] = h;

  const int cc = c * 4 + w;          // global sub-chunk index, time-ordered
  float* p = &ws[(((size_t)b * NCC + cc) * NQ) * NU + u];
#pragma unroll
  for (int q = 0; q < NQ; ++q) p[q * NU] = outq[q];
}

__global__ __launch_bounds__(256)
void lrsig_combine_kernel(const float* __restrict__ ws, float* __restrict__ out)
{
  const int gid = blockIdx.x * blockDim.x + threadIdx.x;   // 0..2047
  const int u = gid & 63;
  const int b = gid >> 6;
  float c1 = 0.f, c3 = 0.f, cA = 0.f, c6 = 0.f, cP = 0.f, cQ = 0.f, o = 0.f;
  for (int cc = 0; cc < NCC; ++cc) {
    const float* p = &ws[(((size_t)b * NCC + cc) * NQ) * NU + u];
    float q[NQ];
#pragma unroll
    for (int i = 0; i < NQ; ++i) q[i] = p[i * NU];
    o  += q[0] + q[1]*c1 + q[2]*c3 + q[3]*cA + q[4]*c6 + q[5]*cP + q[6]*cQ;
    cA += q[13]*c3 + q[9];             // uses c3_in
    cQ += q[15]*cP + q[16]*c6 + q[12]; // uses cP_in, c6_in
    cP += q[14]*c6 + q[11];            // uses c6_in
    c1 += q[7]; c3 += q[8]; c6 += q[10];
  }
  out[gid] = o;
}

extern "C" void kernel_launch(void* const* d_in, const int* in_sizes, int n_in,
                              void* d_out, int out_size, void* d_ws, size_t ws_size,
                              hipStream_t stream) {
  const float* X  = (const float*)d_in[0];   // (32, 2048, 63) fp32
  const float* Kw = (const float*)d_in[1];   // (64, 10, 64)   fp32
  float* out = (float*)d_out;                // (32, 64)       fp32
  float* ws  = (float*)d_ws;                 // 32*128*17*64*4 = 17.8 MB

  hipLaunchKernelGGL(lrsig_chunk_kernel, dim3(32, 32), dim3(256), 0, stream,
                     X, Kw, ws);
  hipLaunchKernelGGL(lrsig_combine_kernel, dim3(8), dim3(256), 0, stream,
                     ws, out);
}

// Round 7
// 83.544 us; speedup vs baseline: 1.9143x; 1.3931x over previous
//
#include <hip/hip_runtime.h>

// LowRankSig_HigherOrder: B=32, T=2048, F=64 (time + 63), K=10 tensors, U=64 units.
// Affine-scan decomposition (validated exact rounds 1-6). Each wave (64 lanes =
// 64 units) handles a 16-row sub-chunk in ONE fused f-pass (acc[16][10]), scans
// it (chains A/B/C), then the 4 per-wave affine maps are composed in LDS
// (round-2-validated composition) into one 64-row map per WG. A tiny second
// kernel folds the 32 maps per (b,u).
//
// Round-7 changes vs round 6 (116 us; VGPR=108 + ~100 AGPRs -> accvgpr copy
// overhead in the f-loop and only 2 waves/SIMD):
//  - __launch_bounds__(256, 1): min-waves=1 => full 512-reg budget, so the
//    allocator can hold acc[16][10] (~190 regs total) in ARCH VGPRs with no
//    AGPR round-trips. (r2-r4 showed hints DEMANDING >=4 waves/EU shrink the
//    file and spill; this hint is the opposite direction.)
//  - In-kernel composition of the 4 wave maps -> ws 17.8 MB -> 4.45 MB and
//    combine folds 32 maps instead of 128.
//  - 1-pass shape kept deliberately: k-split doubles LDS b128 traffic
//    (41 us/CU pipe floor), row-split doubles Kw L2 traffic (39 us) --
//    both would become co-bottlenecks vs the 34 us FMA floor.

#define TT 2048
#define NFX 63
#define KT 10
#define NU 64
#define NQ 17
#define NCC 32       // 64-row chunks per batch (ws layout, after composition)
#define TSTRIDE 68   // padded row stride (floats) for dXa [f][row], 64 rows

enum {Qo=0, Qa1, Qa3, QaA, Qa6, QaP, QaQ, Qd1, Qd3, QdA, Qd6, QdP, QdQ,
      QtA3, QtP6, QtQP, QtQ6};

// compose earlier map q1 with later map q2 -> r (family closed; r2-validated)
__device__ __forceinline__ void compose_maps(const float* q1, const float* q2,
                                             float* r)
{
  r[Qo]  = q1[Qo] + q2[Qo]
         + q2[Qa1]*q1[Qd1] + q2[Qa3]*q1[Qd3] + q2[QaA]*q1[QdA]
         + q2[Qa6]*q1[Qd6] + q2[QaP]*q1[QdP] + q2[QaQ]*q1[QdQ];
  r[Qa1] = q1[Qa1] + q2[Qa1];
  r[Qa3] = q1[Qa3] + q2[Qa3] + q1[QtA3]*q2[QaA];
  r[QaA] = q1[QaA] + q2[QaA];
  r[Qa6] = q1[Qa6] + q2[Qa6] + q1[QtP6]*q2[QaP] + q1[QtQ6]*q2[QaQ];
  r[QaP] = q1[QaP] + q2[QaP] + q1[QtQP]*q2[QaQ];
  r[QaQ] = q1[QaQ] + q2[QaQ];
  r[Qd1] = q1[Qd1] + q2[Qd1];
  r[Qd3] = q1[Qd3] + q2[Qd3];
  r[QdA] = q1[QdA] + q2[QdA] + q2[QtA3]*q1[Qd3];
  r[Qd6] = q1[Qd6] + q2[Qd6];
  r[QdP] = q1[QdP] + q2[QdP] + q2[QtP6]*q1[Qd6];
  r[QdQ] = q1[QdQ] + q2[QdQ] + q2[QtQP]*q1[QdP] + q2[QtQ6]*q1[Qd6];
  r[QtA3] = q1[QtA3] + q2[QtA3];
  r[QtP6] = q1[QtP6] + q2[QtP6];
  r[QtQP] = q1[QtQP] + q2[QtQP];
  r[QtQ6] = q1[QtQ6] + q2[QtQ6] + q2[QtQP]*q1[QtP6];
}

__global__ __launch_bounds__(256, 1)
void lrsig_chunk_kernel(const float* __restrict__ X,
                        const float* __restrict__ Kw,
                        float* __restrict__ ws)
{
  // 4352 floats = 17408 B: dXa tile [64][TSTRIDE] during compute, then the
  // 4 x 17 x 64 map-composition buffer (same size) after a barrier.
  __shared__ float smem[64 * TSTRIDE];

  const int b = blockIdx.y;
  const int c = blockIdx.x;          // 0..31, 64 rows per WG
  const int tid = threadIdx.x;
  const int u = tid & 63;
  const int w = tid >> 6;            // wave 0..3, rows [16w, 16w+16)
  const int t0 = c * 64;

  // ---- stage diff tile: dXa[f][r] = Xa[b,t0+r,f] - Xa[b,t0+r-1,f] (0 at t=0)
  for (int idx = tid; idx < 64 * NFX; idx += 256) {
    int row = idx / NFX;
    int col = idx - row * NFX;
    int gt = t0 + row;
    float d;
    if (gt == 0) d = 0.f;
    else {
      const float* px = &X[((size_t)b * TT + gt) * NFX + col];
      d = px[0] - px[-NFX];
    }
    smem[(col + 1) * TSTRIDE + row] = d;
  }
  if (tid < 64) {
    smem[tid] = (t0 + tid == 0) ? 0.f : (2.0f / 2047.0f);   // time feature f=0
  }
  __syncthreads();

  const int rowbase = 16 * w;

  // ---- single fused M-diff pass: acc[t][k] for 16 rows x 10 tensors ----
  float acc[16][10];
#pragma unroll
  for (int t = 0; t < 16; ++t)
#pragma unroll
    for (int k = 0; k < 10; ++k) acc[t][k] = 0.f;

  {
    const float* kp = &Kw[u];          // [f][k][u]: k stride NU, f stride KT*NU
    float kvn[10];
#pragma unroll
    for (int k = 0; k < 10; ++k) kvn[k] = kp[k * NU];

#pragma unroll 2
    for (int f = 0; f < 64; ++f) {
      float kv[10];
#pragma unroll
      for (int k = 0; k < 10; ++k) kv[k] = kvn[k];
      kp += KT * NU;
      if (f < 63) {
#pragma unroll
        for (int k = 0; k < 10; ++k) kvn[k] = kp[k * NU];
      }
      const float* xb = &smem[f * TSTRIDE + rowbase];
#pragma unroll
      for (int r4 = 0; r4 < 4; ++r4) {
        float4 v = *reinterpret_cast<const float4*>(xb + 4 * r4);
#pragma unroll
        for (int k = 0; k < 10; ++k) {
          acc[4*r4+0][k] = fmaf(v.x, kv[k], acc[4*r4+0][k]);
          acc[4*r4+1][k] = fmaf(v.y, kv[k], acc[4*r4+1][k]);
          acc[4*r4+2][k] = fmaf(v.z, kv[k], acc[4*r4+2][k]);
          acc[4*r4+3][k] = fmaf(v.w, kv[k], acc[4*r4+3][k]);
        }
      }
    }
  }

  // ---- fused scan over the 16 rows (chains A/B/C are independent) ----
  float o = 0.f, a1 = 0.f, lc1 = 0.f;
  float a3 = 0.f, aA = 0.f, lc3 = 0.f, lcA = 0.f, g4 = 0.f;
  float a6 = 0.f, aP = 0.f, aQ = 0.f;
  float lc6 = 0.f, lcP = 0.f, lcQ = 0.f, g7 = 0.f, g8 = 0.f, h = 0.f;

#pragma unroll
  for (int t = 0; t < 16; ++t) {
    float m0 = acc[t][0], m1 = acc[t][1], m2 = acc[t][2];
    float m3 = acc[t][3], m4 = acc[t][4], m5 = acc[t][5];
    float m6 = acc[t][6], m7 = acc[t][7], m8 = acc[t][8], m9 = acc[t][9];

    // chain A (level 0 + m=1)
    o   += m0 + m2 * (lc1 + 0.5f * m1);
    a1  += m2;
    lc1 += m1;

    // chain B (m=2)
    {
      float s0 = m4 * lc3;
      float s1 = 0.5f * m4 * m3;
      o   += m5 * (lcA + 0.5f * s0 + (1.f/3.f) * s1);
      a3  += m5 * (g4 + 0.5f * m4);
      aA  += m5;
      lcA += s0 + s1;
      g4  += m4;
      lc3 += m3;
    }

    // chain C (m=3)
    {
      float p0 = m7 * lc6;
      float p1 = 0.5f * m7 * m6;
      float q0 = m8 * lcP;
      float q1 = 0.5f * m8 * p0;
      float q2 = (1.f/3.f) * m8 * p1;
      o   += m9 * (lcQ + 0.5f * q0 + (1.f/3.f) * q1 + 0.25f * q2);
      a6  += m9 * (h + m8 * (0.5f * g7 + (1.f/6.f) * m7));
      aP  += m9 * (g8 + 0.5f * m8);
      aQ  += m9;
      h   += m8 * (g7 + 0.5f * m7);   // exclusive g7, before update
      lcP += p0 + p1;
      lcQ += q0 + q1 + q2;
      g7 += m7; g8 += m8; lc6 += m6;
    }
  }

  // ---- deposit the 4 wave maps in LDS (reuse smem; all dXa reads done) ----
  __syncthreads();
  {
    float* p = &smem[(w * NQ) * NU + u];
    p[Qo  * NU] = o;
    p[Qa1 * NU] = a1;  p[Qa3 * NU] = a3;  p[QaA * NU] = aA;
    p[Qa6 * NU] = a6;  p[QaP * NU] = aP;  p[QaQ * NU] = aQ;
    p[Qd1 * NU] = lc1; p[Qd3 * NU] = lc3; p[QdA * NU] = lcA;
    p[Qd6 * NU] = lc6; p[QdP * NU] = lcP; p[QdQ * NU] = lcQ;
    p[QtA3* NU] = g4;  p[QtP6* NU] = g7;  p[QtQP* NU] = g8;  p[QtQ6* NU] = h;
  }
  __syncthreads();

  // ---- stage 1: compose (0,1)->slot0 and (2,3)->slot2 (128 threads) ----
  if (tid < 2 * NU) {
    const int pr = tid >> 6;           // pair 0 or 1
    const int uu = tid & 63;
    float q1v[NQ], q2v[NQ], r[NQ];
#pragma unroll
    for (int q = 0; q < NQ; ++q) {
      q1v[q] = smem[((2*pr)     * NQ + q) * NU + uu];
      q2v[q] = smem[((2*pr + 1) * NQ + q) * NU + uu];
    }
    compose_maps(q1v, q2v, r);
#pragma unroll
    for (int q = 0; q < NQ; ++q)
      smem[((2*pr) * NQ + q) * NU + uu] = r[q];
  }
  __syncthreads();

  // ---- stage 2: compose slot0, slot2 -> global ws (64 threads) ----
  if (tid < NU) {
    const int uu = tid;
    float q1v[NQ], q2v[NQ], r[NQ];
#pragma unroll
    for (int q = 0; q < NQ; ++q) {
      q1v[q] = smem[(0 * NQ + q) * NU + uu];
      q2v[q] = smem[(2 * NQ + q) * NU + uu];
    }
    compose_maps(q1v, q2v, r);
    float* p = &ws[(((size_t)b * NCC + c) * NQ) * NU + uu];
#pragma unroll
    for (int q = 0; q < NQ; ++q) p[q * NU] = r[q];
  }
}

__global__ __launch_bounds__(256)
void lrsig_combine_kernel(const float* __restrict__ ws, float* __restrict__ out)
{
  const int gid = blockIdx.x * blockDim.x + threadIdx.x;   // 0..2047
  const int u = gid & 63;
  const int b = gid >> 6;
  float c1 = 0.f, c3 = 0.f, cA = 0.f, c6 = 0.f, cP = 0.f, cQ = 0.f, o = 0.f;
  for (int cc = 0; cc < NCC; ++cc) {
    const float* p = &ws[(((size_t)b * NCC + cc) * NQ) * NU + u];
    float q[NQ];
#pragma unroll
    for (int i = 0; i < NQ; ++i) q[i] = p[i * NU];
    o  += q[0] + q[1]*c1 + q[2]*c3 + q[3]*cA + q[4]*c6 + q[5]*cP + q[6]*cQ;
    cA += q[13]*c3 + q[9];             // uses c3_in
    cQ += q[15]*cP + q[16]*c6 + q[12]; // uses cP_in, c6_in
    cP += q[14]*c6 + q[11];            // uses c6_in
    c1 += q[7]; c3 += q[8]; c6 += q[10];
  }
  out[gid] = o;
}

extern "C" void kernel_launch(void* const* d_in, const int* in_sizes, int n_in,
                              void* d_out, int out_size, void* d_ws, size_t ws_size,
                              hipStream_t stream) {
  const float* X  = (const float*)d_in[0];   // (32, 2048, 63) fp32
  const float* Kw = (const float*)d_in[1];   // (64, 10, 64)   fp32
  float* out = (float*)d_out;                // (32, 64)       fp32
  float* ws  = (float*)d_ws;                 // 32*32*17*64*4 = 4.45 MB

  hipLaunchKernelGGL(lrsig_chunk_kernel, dim3(32, 32), dim3(256), 0, stream,
                     X, Kw, ws);
  hipLaunchKernelGGL(lrsig_combine_kernel, dim3(8), dim3(256), 0, stream,
                     ws, out);
}

// Round 8
// 70.354 us; speedup vs baseline: 2.2732x; 1.1875x over previous
//
#include <hip/hip_runtime.h>

// LowRankSig_HigherOrder: B=32, T=2048, F=64 (time + 63), K=10 tensors, U=64 units.
// Round 8: einsum moved to MFMA (bf16 2-term split, 3 products: hh + lh + hl,
// rel err ~2^-17 -- absmax budget 7.2e-2 on |out|<=500 allows it).
//
// Structure per WG (256 thr = 4 waves, 64 t-rows):
//   1. stage dXa (time+X diffs) as bf16 hi/lo into XOR-swizzled LDS [row][f]
//   2. wave (rt = w>>1, ub = w&1) computes D = dXa[rt*32..+31][:] x Kw_bf16[:][n]
//      for n-tiles nt=0..9 (n = nt*64 + ub*32 + col) via mfma_f32_32x32x16_bf16,
//      acc[10] x f32x16 lives in AGPRs natively (no VALU round-trips).
//   3. C/D layout (HW-verified m74/m101): col=lane&31, row=(reg&3)+8*(reg>>2)
//      +4*(lane>>5) => each lane holds 4-row runs g=2j+hi8 for one u.
//      Per-lane 4-row affine-map scan (r1-r7-validated formulas), maps to LDS.
//   4. LDS composition tree (r2/r7-validated compose): 8 runs -> 32-row ->
//      64-row map -> ws. Tiny combine kernel folds 32 maps per (b,u).
// Prep kernel pre-splits Kw into bf16 hi/lo planes in ws, layout [n][f] so
// B-frags are direct 16-B global loads (Kw is L2-resident, 160 KB).

#define TT 2048
#define NFX 63
#define KT 10
#define NU 64
#define NQ 17
#define NCC 32       // 64-row chunks per batch (ws map layout)

#define MAPS_BYTES (32u * NCC * NQ * NU * 4u)          // 4,456,448 B
#define KWB_ELEMS  (640u * 64u)                        // per plane

typedef __attribute__((ext_vector_type(16))) float f32x16v;
typedef __attribute__((ext_vector_type(8)))  short bf16x8v;

enum {Qo=0, Qa1, Qa3, QaA, Qa6, QaP, QaQ, Qd1, Qd3, QdA, Qd6, QdP, QdQ,
      QtA3, QtP6, QtQP, QtQ6};

__device__ __forceinline__ unsigned short bf16_rne(float x) {
  unsigned int u = __float_as_uint(x);
  unsigned int r = (u + 0x7FFFu + ((u >> 16) & 1u)) >> 16;
  return (unsigned short)r;
}
__device__ __forceinline__ float bf16f(unsigned short h) {
  return __uint_as_float(((unsigned int)h) << 16);
}

// compose earlier map q1 with later map q2 -> r (family closed; r2/r7-validated)
__device__ __forceinline__ void compose_maps(const float* q1, const float* q2,
                                             float* r)
{
  r[Qo]  = q1[Qo] + q2[Qo]
         + q2[Qa1]*q1[Qd1] + q2[Qa3]*q1[Qd3] + q2[QaA]*q1[QdA]
         + q2[Qa6]*q1[Qd6] + q2[QaP]*q1[QdP] + q2[QaQ]*q1[QdQ];
  r[Qa1] = q1[Qa1] + q2[Qa1];
  r[Qa3] = q1[Qa3] + q2[Qa3] + q1[QtA3]*q2[QaA];
  r[QaA] = q1[QaA] + q2[QaA];
  r[Qa6] = q1[Qa6] + q2[Qa6] + q1[QtP6]*q2[QaP] + q1[QtQ6]*q2[QaQ];
  r[QaP] = q1[QaP] + q2[QaP] + q1[QtQP]*q2[QaQ];
  r[QaQ] = q1[QaQ] + q2[QaQ];
  r[Qd1] = q1[Qd1] + q2[Qd1];
  r[Qd3] = q1[Qd3] + q2[Qd3];
  r[QdA] = q1[QdA] + q2[QdA] + q2[QtA3]*q1[Qd3];
  r[Qd6] = q1[Qd6] + q2[Qd6];
  r[QdP] = q1[QdP] + q2[QdP] + q2[QtP6]*q1[Qd6];
  r[QdQ] = q1[QdQ] + q2[QdQ] + q2[QtQP]*q1[QdP] + q2[QtQ6]*q1[Qd6];
  r[QtA3] = q1[QtA3] + q2[QtA3];
  r[QtP6] = q1[QtP6] + q2[QtP6];
  r[QtQP] = q1[QtQP] + q2[QtQP];
  r[QtQ6] = q1[QtQ6] + q2[QtQ6] + q2[QtQP]*q1[QtP6];
}

// ---- prep: split Kw (64 f x 10 k x 64 u fp32) into bf16 hi/lo planes,
//      layout [n = k*64+u][f] so B-frags are contiguous 16-B loads ----
__global__ __launch_bounds__(256)
void lrsig_prep_kernel(const float* __restrict__ Kw,
                       unsigned short* __restrict__ kwb)
{
  int e = blockIdx.x * 256 + threadIdx.x;    // 0..40959
  int n = e >> 6, f = e & 63;
  int k = n >> 6, u = n & 63;
  float x = Kw[(f * KT + k) * NU + u];
  unsigned short hi = bf16_rne(x);
  unsigned short lo = bf16_rne(x - bf16f(hi));
  kwb[(size_t)n * 64 + f] = hi;
  kwb[KWB_ELEMS + (size_t)n * 64 + f] = lo;
}

__global__ __launch_bounds__(256)
void lrsig_chunk_kernel(const float* __restrict__ X,
                        const unsigned short* __restrict__ kwb,
                        float* __restrict__ wmaps)
{
  // 69632 B: staging phase uses [0,16384) as dXa bf16 hi/lo tiles
  // ([64 rows][128 B] each, XOR-swizzled); scan phase reuses all of it as
  // the map buffer [2 rt][8 g][17 q][64 u] floats (barrier-separated).
  __shared__ __align__(16) float smemf[2 * 8 * NQ * NU];
  char* smem = (char*)smemf;

  const int b   = blockIdx.y;
  const int c   = blockIdx.x;        // 0..31, 64 rows per WG
  const int tid = threadIdx.x;
  const int l   = tid & 63;
  const int w   = tid >> 6;          // wave 0..3
  const int rt  = w >> 1;            // row-tile (rows rt*32 .. +31)
  const int ub  = w & 1;             // u-block  (u = ub*32 + col)
  const int col = l & 31;
  const int hi8 = l >> 5;            // k-half within frag
  const int t0  = c * 64;

  // ---- stage dXa tile as bf16 hi/lo, swizzled: byte = row*128 + (2f ^ ((row&7)<<4))
  for (int idx = tid; idx < 64 * NFX; idx += 256) {
    int row = idx / NFX;
    int fcol = idx - row * NFX + 1;          // features 1..63
    int gt = t0 + row;
    float d;
    if (gt == 0) d = 0.f;
    else {
      const float* px = &X[((size_t)b * TT + gt) * NFX + (fcol - 1)];
      d = px[0] - px[-NFX];
    }
    unsigned short h = bf16_rne(d);
    unsigned short lo = bf16_rne(d - bf16f(h));
    int byte = row * 128 + ((2 * fcol) ^ ((row & 7) << 4));
    *(unsigned short*)(smem + byte)        = h;
    *(unsigned short*)(smem + 8192 + byte) = lo;
  }
  if (tid < 64) {                            // time feature f=0
    int row = tid;
    float d = (t0 + row == 0) ? 0.f : (2.0f / 2047.0f);
    unsigned short h = bf16_rne(d);
    unsigned short lo = bf16_rne(d - bf16f(h));
    int byte = row * 128 + ((0) ^ ((row & 7) << 4));
    *(unsigned short*)(smem + byte)        = h;
    *(unsigned short*)(smem + 8192 + byte) = lo;
  }
  __syncthreads();

  // ---- MFMA phase: acc[nt] (f32x16) = sum_f dXa[rows][f] * Kw[f][n-tile nt]
  f32x16v acc[10];
#pragma unroll
  for (int nt = 0; nt < 10; ++nt)
#pragma unroll
    for (int i = 0; i < 16; ++i) acc[nt][i] = 0.f;

  {
    const int row = rt * 32 + col;           // A: lane row = l&31
#pragma unroll
    for (int ks = 0; ks < 4; ++ks) {         // K=64 in 4 steps of 16
      const int f0 = ks * 16 + hi8 * 8;      // lane's 8 k-elems
      const int abyte = row * 128 + ((2 * f0) ^ ((row & 7) << 4));
      bf16x8v ah = *(const bf16x8v*)(smem + abyte);
      bf16x8v al = *(const bf16x8v*)(smem + 8192 + abyte);
#pragma unroll
      for (int nt = 0; nt < 10; ++nt) {
        const int n = nt * 64 + ub * 32 + col;   // B: lane col = l&31
        bf16x8v bh = *(const bf16x8v*)(kwb + (size_t)n * 64 + f0);
        bf16x8v bl = *(const bf16x8v*)(kwb + KWB_ELEMS + (size_t)n * 64 + f0);
        acc[nt] = __builtin_amdgcn_mfma_f32_32x32x16_bf16(ah, bh, acc[nt], 0, 0, 0);
        acc[nt] = __builtin_amdgcn_mfma_f32_32x32x16_bf16(al, bh, acc[nt], 0, 0, 0);
        acc[nt] = __builtin_amdgcn_mfma_f32_32x32x16_bf16(ah, bl, acc[nt], 0, 0, 0);
      }
    }
  }

  __syncthreads();   // all LDS A-reads done; smem becomes the map buffer

  // ---- per-lane scan of 4-row runs; D row = (reg&3)+8*(reg>>2)+4*hi8 ----
  const int u_t = ub * 32 + col;
#pragma unroll
  for (int j = 0; j < 4; ++j) {              // run j: regs 4j..4j+3, rows 8j+4*hi8+i
    float o=0.f, a1=0.f, lc1=0.f;
    float a3=0.f, aA=0.f, lc3=0.f, lcA=0.f, g4=0.f;
    float a6=0.f, aP=0.f, aQ=0.f;
    float lc6=0.f, lcP=0.f, lcQ=0.f, g7=0.f, g8=0.f, hh=0.f;
#pragma unroll
    for (int i = 0; i < 4; ++i) {
      const int r = 4 * j + i;
      float m0=acc[0][r], m1=acc[1][r], m2=acc[2][r], m3=acc[3][r];
      float m4=acc[4][r], m5=acc[5][r], m6=acc[6][r], m7=acc[7][r];
      float m8=acc[8][r], m9=acc[9][r];
      // chain A
      o   += m0 + m2 * (lc1 + 0.5f * m1);
      a1  += m2;
      lc1 += m1;
      // chain B
      {
        float s0 = m4 * lc3;
        float s1 = 0.5f * m4 * m3;
        o   += m5 * (lcA + 0.5f * s0 + (1.f/3.f) * s1);
        a3  += m5 * (g4 + 0.5f * m4);
        aA  += m5;
        lcA += s0 + s1;
        g4  += m4;
        lc3 += m3;
      }
      // chain C
      {
        float p0 = m7 * lc6;
        float p1 = 0.5f * m7 * m6;
        float q0 = m8 * lcP;
        float q1 = 0.5f * m8 * p0;
        float q2 = (1.f/3.f) * m8 * p1;
        o   += m9 * (lcQ + 0.5f * q0 + (1.f/3.f) * q1 + 0.25f * q2);
        a6  += m9 * (hh + m8 * (0.5f * g7 + (1.f/6.f) * m7));
        aP  += m9 * (g8 + 0.5f * m8);
        aQ  += m9;
        hh  += m8 * (g7 + 0.5f * m7);   // exclusive g7, before update
        lcP += p0 + p1;
        lcQ += q0 + q1 + q2;
        g7 += m7; g8 += m8; lc6 += m6;
      }
    }
    const int g = 2 * j + hi8;               // rows 4g..4g+3 of the 32-row tile
    float* p = &smemf[((rt * 8 + g) * NQ) * NU + u_t];
    p[Qo  *NU]=o;   p[Qa1 *NU]=a1;  p[Qa3 *NU]=a3;  p[QaA *NU]=aA;
    p[Qa6 *NU]=a6;  p[QaP *NU]=aP;  p[QaQ *NU]=aQ;
    p[Qd1 *NU]=lc1; p[Qd3 *NU]=lc3; p[QdA *NU]=lcA;
    p[Qd6 *NU]=lc6; p[QdP *NU]=lcP; p[QdQ *NU]=lcQ;
    p[QtA3*NU]=g4;  p[QtP6*NU]=g7;  p[QtQP*NU]=g8;  p[QtQ6*NU]=hh;
  }
  __syncthreads();

  // ---- composition tree: (0,1)(2,3)(4,5)(6,7) -> (0,2)(4,6) -> (0,4) -> rt pair
  // L1: 512 jobs, 2 per thread
  for (int job = tid; job < 512; job += 256) {
    const int uu = job & 63, p = (job >> 6) & 3, rr = job >> 8;
    float q1v[NQ], q2v[NQ], rv[NQ];
    const float* s1 = &smemf[((rr * 8 + 2*p    ) * NQ) * NU + uu];
    const float* s2 = &smemf[((rr * 8 + 2*p + 1) * NQ) * NU + uu];
#pragma unroll
    for (int q = 0; q < NQ; ++q) { q1v[q] = s1[q*NU]; q2v[q] = s2[q*NU]; }
    compose_maps(q1v, q2v, rv);
    float* d = &smemf[((rr * 8 + 2*p) * NQ) * NU + uu];
#pragma unroll
    for (int q = 0; q < NQ; ++q) d[q*NU] = rv[q];
  }
  __syncthreads();
  // L2: 256 jobs
  {
    const int uu = tid & 63, p2 = (tid >> 6) & 1, rr = tid >> 7;
    float q1v[NQ], q2v[NQ], rv[NQ];
    const float* s1 = &smemf[((rr * 8 + 4*p2    ) * NQ) * NU + uu];
    const float* s2 = &smemf[((rr * 8 + 4*p2 + 2) * NQ) * NU + uu];
#pragma unroll
    for (int q = 0; q < NQ; ++q) { q1v[q] = s1[q*NU]; q2v[q] = s2[q*NU]; }
    compose_maps(q1v, q2v, rv);
    float* d = &smemf[((rr * 8 + 4*p2) * NQ) * NU + uu];
#pragma unroll
    for (int q = 0; q < NQ; ++q) d[q*NU] = rv[q];
  }
  __syncthreads();
  // L3: 128 jobs -> 32-row maps in slots (rr, 0)
  if (tid < 128) {
    const int uu = tid & 63, rr = tid >> 6;
    float q1v[NQ], q2v[NQ], rv[NQ];
    const float* s1 = &smemf[((rr * 8 + 0) * NQ) * NU + uu];
    const float* s2 = &smemf[((rr * 8 + 4) * NQ) * NU + uu];
#pragma unroll
    for (int q = 0; q < NQ; ++q) { q1v[q] = s1[q*NU]; q2v[q] = s2[q*NU]; }
    compose_maps(q1v, q2v, rv);
    float* d = &smemf[((rr * 8 + 0) * NQ) * NU + uu];
#pragma unroll
    for (int q = 0; q < NQ; ++q) d[q*NU] = rv[q];
  }
  __syncthreads();
  // L4: 64 jobs -> 64-row WG map -> ws
  if (tid < 64) {
    const int uu = tid;
    float q1v[NQ], q2v[NQ], rv[NQ];
    const float* s1 = &smemf[((0 * 8 + 0) * NQ) * NU + uu];
    const float* s2 = &smemf[((1 * 8 + 0) * NQ) * NU + uu];
#pragma unroll
    for (int q = 0; q < NQ; ++q) { q1v[q] = s1[q*NU]; q2v[q] = s2[q*NU]; }
    compose_maps(q1v, q2v, rv);
    float* p = &wmaps[(((size_t)b * NCC + c) * NQ) * NU + uu];
#pragma unroll
    for (int q = 0; q < NQ; ++q) p[q * NU] = rv[q];
  }
}

__global__ __launch_bounds__(256)
void lrsig_combine_kernel(const float* __restrict__ ws, float* __restrict__ out)
{
  const int gid = blockIdx.x * blockDim.x + threadIdx.x;   // 0..2047
  const int u = gid & 63;
  const int b = gid >> 6;
  float c1 = 0.f, c3 = 0.f, cA = 0.f, c6 = 0.f, cP = 0.f, cQ = 0.f, o = 0.f;
  for (int cc = 0; cc < NCC; ++cc) {
    const float* p = &ws[(((size_t)b * NCC + cc) * NQ) * NU + u];
    float q[NQ];
#pragma unroll
    for (int i = 0; i < NQ; ++i) q[i] = p[i * NU];
    o  += q[0] + q[1]*c1 + q[2]*c3 + q[3]*cA + q[4]*c6 + q[5]*cP + q[6]*cQ;
    cA += q[13]*c3 + q[9];             // uses c3_in
    cQ += q[15]*cP + q[16]*c6 + q[12]; // uses cP_in, c6_in
    cP += q[14]*c6 + q[11];            // uses c6_in
    c1 += q[7]; c3 += q[8]; c6 += q[10];
  }
  out[gid] = o;
}

extern "C" void kernel_launch(void* const* d_in, const int* in_sizes, int n_in,
                              void* d_out, int out_size, void* d_ws, size_t ws_size,
                              hipStream_t stream) {
  const float* X  = (const float*)d_in[0];   // (32, 2048, 63) fp32
  const float* Kw = (const float*)d_in[1];   // (64, 10, 64)   fp32
  float* out = (float*)d_out;                // (32, 64)       fp32
  float* wmaps = (float*)d_ws;               // maps: 4.45 MB
  unsigned short* kwb = (unsigned short*)((char*)d_ws + MAPS_BYTES); // 160 KB

  hipLaunchKernelGGL(lrsig_prep_kernel, dim3(160), dim3(256), 0, stream,
                     Kw, kwb);
  hipLaunchKernelGGL(lrsig_chunk_kernel, dim3(NCC, 32), dim3(256), 0, stream,
                     X, kwb, wmaps);
  hipLaunchKernelGGL(lrsig_combine_kernel, dim3(8), dim3(256), 0, stream,
                     wmaps, out);
}